// Round 2
// baseline (4532.422 us; speedup 1.0000x reference)
//
#include <hip/hip_runtime.h>
#include <math.h>

#define L_DIM 3072
#define B_DIM 64
#define H_DIM 256
#define HP 257          // padded LDS stride (bank-conflict-free strided reads)
#define TWO_PI_F 6.28318530717958647692f
#define EPS_F 1e-6f

__device__ __forceinline__ float mod2pi(float x){
    float r = fmodf(x, TWO_PI_F);
    return (r < 0.0f) ? r + TWO_PI_F : r;
}

__global__ __launch_bounds__(256) void init_kernel(const float* __restrict__ zin, float* __restrict__ out){
    int i = blockIdx.x*256 + threadIdx.x;
    if (i < B_DIM*L_DIM) out[i] = zin[i];
    if (i < B_DIM) out[B_DIM*L_DIM + i] = 0.0f;   // zero ldj accumulators
}

// One coupling round, fully fused: stencil -> MLP(2->256->256->48) -> mixture map -> z update + ldj.
// 32 sites per block, 256 threads (4 waves). In-place z update is race-free (see analysis).
__global__ __launch_bounds__(256) void round_kernel(
    float* __restrict__ z, float* __restrict__ ldj,
    const float* __restrict__ W1, const float* __restrict__ b1,
    const float* __restrict__ W2, const float* __restrict__ b2,
    const float* __restrict__ W3, const float* __restrict__ b3,
    int off)
{
    __shared__ float h_lds[32*HP];     // h1 tile, then reused for h2 tile
    __shared__ float p_lds[32*48];     // params tile
    __shared__ float c1_l[32], c2_l[32], u_l[32], zr_l[32];

    const int tid = threadIdx.x;
    const int bid = blockIdx.x;
    const int b  = bid >> 5;           // batch index (32 blocks per batch)
    const int j0 = (bid & 31) << 5;    // first site index of this block
    float* zb = z + b*L_DIM;

    // -------- Phase 0: stencil / context --------
    if (tid < 32){
        int j = j0 + tid;
        int idx = 3*j + off;
        int im2 = idx-2; if (im2 < 0) im2 += L_DIM;
        int im1 = idx-1; if (im1 < 0) im1 += L_DIM;
        int ip1 = idx+1; if (ip1 >= L_DIM) ip1 -= L_DIM;
        int ip2 = idx+2; if (ip2 >= L_DIM) ip2 -= L_DIM;
        float zi  = zb[idx];
        float zm1 = zb[im1];
        float zm2 = zb[im2];
        float zp1 = zb[ip1];
        float zp2 = zb[ip2];
        c1_l[tid] = mod2pi(zm1 - zm2);          // V[idx-1]
        c2_l[tid] = mod2pi(zp2 - zp1);          // V[idx+2]
        float V   = mod2pi(zi - zm1);           // V[idx]
        float u = V * (1.0f/TWO_PI_F);
        u_l[tid] = fminf(fmaxf(u, EPS_F), 1.0f-EPS_F);
        zr_l[tid] = zm1;
    }
    __syncthreads();

    // -------- Phase 1: layer 1, h1[m][k] = tanh(c1*W1[0,k] + c2*W1[1,k] + b1[k]) --------
    {
        float w0 = W1[tid];
        float w1 = W1[H_DIM + tid];
        float bb = b1[tid];
        #pragma unroll 4
        for (int m=0; m<32; m++){
            float pre = fmaf(c1_l[m], w0, fmaf(c2_l[m], w1, bb));
            h_lds[m*HP + tid] = tanhf(pre);
        }
    }
    __syncthreads();

    // -------- Phase 2: layer 2 GEMM (32x256) = h1(32x256) @ W2(256x256) --------
    const int ty = tid >> 4;           // 0..15 : site pair
    const int tx = tid & 15;           // 0..15 : column group
    float acc[2][16];
    #pragma unroll
    for (int mm=0; mm<2; mm++)
        #pragma unroll
        for (int nn=0; nn<16; nn++) acc[mm][nn] = 0.0f;

    const float4* W2v = (const float4*)W2;
    #pragma unroll 2
    for (int k=0; k<H_DIM; k++){
        float a0 = h_lds[(ty*2+0)*HP + k];
        float a1 = h_lds[(ty*2+1)*HP + k];
        const float4* wr = W2v + k*64 + tx;     // column n = q*64 + tx*4 + c
        float4 t0 = wr[0], t1 = wr[16], t2 = wr[32], t3 = wr[48];
        float w[16];
        w[0]=t0.x;  w[1]=t0.y;  w[2]=t0.z;  w[3]=t0.w;
        w[4]=t1.x;  w[5]=t1.y;  w[6]=t1.z;  w[7]=t1.w;
        w[8]=t2.x;  w[9]=t2.y;  w[10]=t2.z; w[11]=t2.w;
        w[12]=t3.x; w[13]=t3.y; w[14]=t3.z; w[15]=t3.w;
        #pragma unroll
        for (int nn=0; nn<16; nn++){
            acc[0][nn] = fmaf(a0, w[nn], acc[0][nn]);
            acc[1][nn] = fmaf(a1, w[nn], acc[1][nn]);
        }
    }
    __syncthreads();   // all h1 reads done; safe to overwrite with h2

    // -------- Phase 3: h2 = tanh(acc + b2) back into LDS --------
    #pragma unroll
    for (int mm=0; mm<2; mm++){
        int m = ty*2 + mm;
        #pragma unroll
        for (int q=0; q<4; q++){
            #pragma unroll
            for (int c=0; c<4; c++){
                int n = q*64 + tx*4 + c;
                h_lds[m*HP + n] = tanhf(acc[mm][q*4+c] + b2[n]);
            }
        }
    }
    __syncthreads();

    // -------- Phase 4: layer 3, params(32x48) = h2 @ W3 + b3 --------
    {
        const int m3 = tid >> 3;       // 0..31 site
        const int ol = tid & 7;        // 0..7  -> 6 consecutive outputs each
        float acc3[6] = {0,0,0,0,0,0};
        const float* W3o = W3 + ol*6;
        for (int k=0; k<H_DIM; k++){
            float hv = h_lds[m3*HP + k];
            const float* w3r = W3o + k*48;
            #pragma unroll
            for (int r=0; r<6; r++) acc3[r] = fmaf(hv, w3r[r], acc3[r]);
        }
        #pragma unroll
        for (int r=0; r<6; r++) p_lds[m3*48 + ol*6 + r] = acc3[r] + b3[ol*6 + r];
    }
    __syncthreads();

    // -------- Phase 5: epilogue (one thread per site) --------
    float ll = 0.0f;
    if (tid < 32){
        const float* p = p_lds + tid*48;   // [0..15] log_scale, [16..31] shift, [32..47] wlogit
        float mx = p[32];
        #pragma unroll
        for (int i=1; i<16; i++) mx = fmaxf(mx, p[32+i]);
        float w[16]; float se = 0.0f;
        #pragma unroll
        for (int i=0; i<16; i++){ w[i] = expf(p[32+i]-mx); se += w[i]; }
        float inv = 0.84f / se;            // (1 - K*MIN_W)/sum

        float u = u_l[tid];
        float a  = u*u;
        float om = 1.0f - u;
        float b_ = om*om;
        float apb = a + b_;
        float s = a / apb;
        float ds_du = 2.0f*u*om / (apb*apb);
        s = fminf(fmaxf(s, EPS_F), 1.0f-EPS_F);
        float logit_s = logf(s) - log1pf(-s);

        float y = 0.0f, dd = 0.0f;
        #pragma unroll
        for (int i=0; i<16; i++){
            float alpha = expf(p[i]);
            float wgt = fmaf(w[i], inv, 0.01f);
            float targ = alpha * (logit_s + p[16+i]);
            float g = 1.0f / (1.0f + expf(-targ));
            y  = fmaf(wgt, g, y);
            dd = fmaf(wgt*alpha, g*(1.0f-g), dd);
        }
        float dy_du = dd / (s*(1.0f-s)) * ds_du;
        ll = logf(dy_du);

        int idx = 3*(j0 + tid) + off;
        zb[idx] = mod2pi(fmaf(TWO_PI_F, y, zr_l[tid]));
    }
    // wave-0 reduction of ll (lanes 32..63 contribute 0), one atomic per block
    if (tid < 64){
        #pragma unroll
        for (int o=32; o>0; o>>=1) ll += __shfl_down(ll, o, 64);
        if (tid == 0) atomicAdd(&ldj[b], ll);
    }
}

extern "C" void kernel_launch(void* const* d_in, const int* in_sizes, int n_in,
                              void* d_out, int out_size, void* d_ws, size_t ws_size,
                              hipStream_t stream) {
    const float* z_in = (const float*)d_in[0];
    const float* W1 = (const float*)d_in[1];
    const float* b1 = (const float*)d_in[2];
    const float* W2 = (const float*)d_in[3];
    const float* b2 = (const float*)d_in[4];
    const float* W3 = (const float*)d_in[5];
    const float* b3 = (const float*)d_in[6];
    float* out = (float*)d_out;
    float* zbuf = out;                      // z worked in-place in d_out
    float* ldj  = out + B_DIM*L_DIM;

    init_kernel<<<(B_DIM*L_DIM + 255)/256, 256, 0, stream>>>(z_in, out);

    for (int t=0; t<12; t++){
        int r = t % 3;
        int off = (r==0) ? 0 : ((r==1) ? 2 : 1);
        round_kernel<<<2048, 256, 0, stream>>>(
            zbuf, ldj,
            W1 + t*2*H_DIM, b1 + t*H_DIM,
            W2 + t*H_DIM*H_DIM, b2 + t*H_DIM,
            W3 + t*H_DIM*48, b3 + t*48,
            off);
    }
}

// Round 3
// 2463.561 us; speedup vs baseline: 1.8398x; 1.8398x over previous
//
#include <hip/hip_runtime.h>
#include <math.h>

#define L_DIM 3072
#define B_DIM 64
#define H_DIM 256
#define HP2 258         // h-tile stride (floats): even -> float2 LDS reads, conflict-free by design
#define PP 49           // p-tile stride: odd -> epilogue reads spread across banks
#define TWO_PI_F 6.28318530717958647692f
#define EPS_F 1e-6f

__device__ __forceinline__ float mod2pi(float x){
    float r = fmodf(x, TWO_PI_F);
    return (r < 0.0f) ? r + TWO_PI_F : r;
}

__global__ __launch_bounds__(256) void init_kernel(const float* __restrict__ zin, float* __restrict__ out){
    int i = blockIdx.x*256 + threadIdx.x;
    if (i < B_DIM*L_DIM) out[i] = zin[i];
    if (i < B_DIM) out[B_DIM*L_DIM + i] = 0.0f;   // zero ldj accumulators
}

// One coupling round, fully fused. 64 sites/block, 256 threads (4 waves), grid 1024.
// Phase-2 GEMM: wave w owns cols [w*64, w*64+64); per k each W2 row is read exactly
// once per block (no redundancy); each thread: 16 sites x 4 cols = 64 FMA per 16B load.
__global__ __launch_bounds__(256) void round_kernel(
    float* __restrict__ z, float* __restrict__ ldj,
    const float* __restrict__ W1, const float* __restrict__ b1,
    const float* __restrict__ W2, const float* __restrict__ b2,
    const float* __restrict__ W3, const float* __restrict__ b3,
    int off)
{
    __shared__ float h_lds[64*HP2];       // 66048 B: h1 tile, then reused for h2
    __shared__ float p_lds[64*PP];        // 12544 B: params
    __shared__ float c1_l[64], c2_l[64], u_l[64], zr_l[64];

    const int tid = threadIdx.x;
    const int bid = blockIdx.x;
    const int b  = bid >> 4;              // batch (16 blocks per batch)
    const int j0 = (bid & 15) << 6;       // first site of block
    float* zb = z + b*L_DIM;

    // -------- Phase 0: stencil / context --------
    if (tid < 64){
        int idx = 3*(j0 + tid) + off;
        int im2 = idx-2; if (im2 < 0) im2 += L_DIM;
        int im1 = idx-1; if (im1 < 0) im1 += L_DIM;
        int ip1 = idx+1; if (ip1 >= L_DIM) ip1 -= L_DIM;
        int ip2 = idx+2; if (ip2 >= L_DIM) ip2 -= L_DIM;
        float zi  = zb[idx];
        float zm1 = zb[im1];
        float zm2 = zb[im2];
        float zp1 = zb[ip1];
        float zp2 = zb[ip2];
        c1_l[tid] = mod2pi(zm1 - zm2);    // V[idx-1]
        c2_l[tid] = mod2pi(zp2 - zp1);    // V[idx+2]
        float V   = mod2pi(zi - zm1);     // V[idx]
        float u = V * (1.0f/TWO_PI_F);
        u_l[tid] = fminf(fmaxf(u, EPS_F), 1.0f-EPS_F);
        zr_l[tid] = zm1;
    }
    __syncthreads();

    // -------- Phase 1: h1[m][k] = tanh(c1*W1[0,k] + c2*W1[1,k] + b1[k]), k = tid --------
    {
        float w0 = W1[tid];
        float w1 = W1[H_DIM + tid];
        float bb = b1[tid];
        #pragma unroll 8
        for (int m=0; m<64; m++){
            float pre = fmaf(c1_l[m], w0, fmaf(c2_l[m], w1, bb));
            h_lds[m*HP2 + tid] = tanhf(pre);
        }
    }
    __syncthreads();

    // -------- Phase 2: h1(64x256) @ W2(256x256) --------
    const int wv  = tid >> 6;             // wave 0..3 -> col slice
    const int lane = tid & 63;
    const int ty = lane >> 4;             // 0..3
    const int tx = lane & 15;             // 0..15
    const int c4 = wv*16 + tx;            // float4 col index within row

    float acc[16][4];
    #pragma unroll
    for (int s=0; s<16; s++){ acc[s][0]=0.f; acc[s][1]=0.f; acc[s][2]=0.f; acc[s][3]=0.f; }

    const float4* __restrict__ W2v = (const float4*)W2;
    #pragma unroll 2
    for (int k=0; k<H_DIM; k+=2){
        float4 wv0 = W2v[k*64 + c4];
        float4 wv1 = W2v[(k+1)*64 + c4];
        float2 av[16];
        #pragma unroll
        for (int s=0; s<16; s++)
            av[s] = *(const float2*)&h_lds[(s*4+ty)*HP2 + k];   // broadcast over tx, banks distinct over ty/s
        #pragma unroll
        for (int s=0; s<16; s++){
            acc[s][0] = fmaf(av[s].x, wv0.x, acc[s][0]);
            acc[s][1] = fmaf(av[s].x, wv0.y, acc[s][1]);
            acc[s][2] = fmaf(av[s].x, wv0.z, acc[s][2]);
            acc[s][3] = fmaf(av[s].x, wv0.w, acc[s][3]);
            acc[s][0] = fmaf(av[s].y, wv1.x, acc[s][0]);
            acc[s][1] = fmaf(av[s].y, wv1.y, acc[s][1]);
            acc[s][2] = fmaf(av[s].y, wv1.z, acc[s][2]);
            acc[s][3] = fmaf(av[s].y, wv1.w, acc[s][3]);
        }
    }
    __syncthreads();      // all h1 reads done

    // -------- Phase 3: h2 = tanh(acc + b2) back into LDS --------
    {
        const int n0 = wv*64 + tx*4;
        float b20 = b2[n0], b21 = b2[n0+1], b22 = b2[n0+2], b23 = b2[n0+3];
        #pragma unroll
        for (int s=0; s<16; s++){
            int m = s*4 + ty;
            float t0 = tanhf(acc[s][0] + b20);
            float t1 = tanhf(acc[s][1] + b21);
            float t2 = tanhf(acc[s][2] + b22);
            float t3 = tanhf(acc[s][3] + b23);
            float2 p0; p0.x = t0; p0.y = t1;
            float2 p1; p1.x = t2; p1.y = t3;
            *(float2*)&h_lds[m*HP2 + n0]     = p0;   // (m*258 + n0) even -> 8B aligned
            *(float2*)&h_lds[m*HP2 + n0 + 2] = p1;
        }
    }
    __syncthreads();

    // -------- Phase 4: params(64x48) = h2 @ W3 + b3 ; 4 threads/site, 12 outputs each --------
    {
        const int m3 = tid >> 2;          // site 0..63
        const int ol = tid & 3;           // output block (12 params each)
        float acc3[12];
        #pragma unroll
        for (int r=0; r<12; r++) acc3[r] = 0.f;
        const float4* __restrict__ W3v = (const float4*)W3;
        const int basev = ol*3;
        #pragma unroll 4
        for (int k=0; k<H_DIM; k++){
            float hv = h_lds[m3*HP2 + k];
            float4 q0 = W3v[k*12 + basev];
            float4 q1 = W3v[k*12 + basev + 1];
            float4 q2 = W3v[k*12 + basev + 2];
            acc3[0] = fmaf(hv, q0.x, acc3[0]);  acc3[1] = fmaf(hv, q0.y, acc3[1]);
            acc3[2] = fmaf(hv, q0.z, acc3[2]);  acc3[3] = fmaf(hv, q0.w, acc3[3]);
            acc3[4] = fmaf(hv, q1.x, acc3[4]);  acc3[5] = fmaf(hv, q1.y, acc3[5]);
            acc3[6] = fmaf(hv, q1.z, acc3[6]);  acc3[7] = fmaf(hv, q1.w, acc3[7]);
            acc3[8] = fmaf(hv, q2.x, acc3[8]);  acc3[9] = fmaf(hv, q2.y, acc3[9]);
            acc3[10]= fmaf(hv, q2.z, acc3[10]); acc3[11]= fmaf(hv, q2.w, acc3[11]);
        }
        #pragma unroll
        for (int r=0; r<12; r++)
            p_lds[m3*PP + ol*12 + r] = acc3[r] + b3[ol*12 + r];
    }
    __syncthreads();

    // -------- Phase 5: epilogue, one thread per site (wave 0) --------
    float ll = 0.0f;
    if (tid < 64){
        const float* p = p_lds + tid*PP;  // [0..15] log_scale, [16..31] shift, [32..47] wlogit
        float mx = p[32];
        #pragma unroll
        for (int i=1; i<16; i++) mx = fmaxf(mx, p[32+i]);
        float w[16]; float se = 0.0f;
        #pragma unroll
        for (int i=0; i<16; i++){ w[i] = expf(p[32+i]-mx); se += w[i]; }
        float inv = 0.84f / se;           // (1 - K*MIN_W)/sum

        float u = u_l[tid];
        float a  = u*u;
        float om = 1.0f - u;
        float b_ = om*om;
        float apb = a + b_;
        float s = a / apb;
        float ds_du = 2.0f*u*om / (apb*apb);
        s = fminf(fmaxf(s, EPS_F), 1.0f-EPS_F);
        float logit_s = logf(s) - log1pf(-s);

        float y = 0.0f, dd = 0.0f;
        #pragma unroll
        for (int i=0; i<16; i++){
            float alpha = expf(p[i]);
            float wgt = fmaf(w[i], inv, 0.01f);
            float targ = alpha * (logit_s + p[16+i]);
            float g = 1.0f / (1.0f + expf(-targ));
            y  = fmaf(wgt, g, y);
            dd = fmaf(wgt*alpha, g*(1.0f-g), dd);
        }
        float dy_du = dd / (s*(1.0f-s)) * ds_du;
        ll = logf(dy_du);

        int idx = 3*(j0 + tid) + off;
        zb[idx] = mod2pi(fmaf(TWO_PI_F, y, zr_l[tid]));
    }
    // wave-0 butterfly reduction of ll, one atomic per block
    if (tid < 64){
        #pragma unroll
        for (int o=32; o>0; o>>=1) ll += __shfl_down(ll, o, 64);
        if (tid == 0) atomicAdd(&ldj[b], ll);
    }
}

extern "C" void kernel_launch(void* const* d_in, const int* in_sizes, int n_in,
                              void* d_out, int out_size, void* d_ws, size_t ws_size,
                              hipStream_t stream) {
    const float* z_in = (const float*)d_in[0];
    const float* W1 = (const float*)d_in[1];
    const float* b1 = (const float*)d_in[2];
    const float* W2 = (const float*)d_in[3];
    const float* b2 = (const float*)d_in[4];
    const float* W3 = (const float*)d_in[5];
    const float* b3 = (const float*)d_in[6];
    float* out = (float*)d_out;
    float* zbuf = out;                    // z worked in-place in d_out
    float* ldj  = out + B_DIM*L_DIM;

    init_kernel<<<(B_DIM*L_DIM + 255)/256, 256, 0, stream>>>(z_in, out);

    for (int t=0; t<12; t++){
        int r = t % 3;
        int off = (r==0) ? 0 : ((r==1) ? 2 : 1);
        round_kernel<<<1024, 256, 0, stream>>>(
            zbuf, ldj,
            W1 + t*2*H_DIM, b1 + t*H_DIM,
            W2 + t*H_DIM*H_DIM, b2 + t*H_DIM,
            W3 + t*H_DIM*48, b3 + t*48,
            off);
    }
}

// Round 4
// 1939.555 us; speedup vs baseline: 2.3368x; 1.2702x over previous
//
#include <hip/hip_runtime.h>
#include <math.h>

#define L_DIM 3072
#define B_DIM 64
#define H_DIM 256
#define HP2 260         // h-tile stride (floats): 260*4=1040 B, 16B-aligned rows -> b128 LDS ops legal
#define PP 49           // p-tile stride: odd -> epilogue reads spread across banks
#define TWO_PI_F 6.28318530717958647692f
#define EPS_F 1e-6f

__device__ __forceinline__ float mod2pi(float x){
    float q = floorf(x * (1.0f/TWO_PI_F));
    return fmaf(-TWO_PI_F, q, x);
}

// tanh(x) = 1 - 2/(e^{2x}+1); __expf -> v_exp_f32, __fdividef -> v_rcp_f32.
// Abs err ~1e-7, exact saturation at +/-1 (e^{2x} -> inf/0). Plenty within threshold.
__device__ __forceinline__ float fast_tanh(float x){
    float t = __expf(2.0f*x);
    return 1.0f - __fdividef(2.0f, t + 1.0f);
}

__global__ __launch_bounds__(256) void init_kernel(const float* __restrict__ zin, float* __restrict__ out){
    int i = blockIdx.x*256 + threadIdx.x;
    if (i < B_DIM*L_DIM) out[i] = zin[i];
    if (i < B_DIM) out[B_DIM*L_DIM + i] = 0.0f;   // zero ldj accumulators
}

// One coupling round, fully fused. 64 sites/block, 256 threads (4 waves), grid 1024.
__global__ __launch_bounds__(256) void round_kernel(
    float* __restrict__ z, float* __restrict__ ldj,
    const float* __restrict__ W1, const float* __restrict__ b1,
    const float* __restrict__ W2, const float* __restrict__ b2,
    const float* __restrict__ W3, const float* __restrict__ b3,
    int off)
{
    __shared__ float h_lds[64*HP2];       // 66560 B: h1 tile, then reused for h2
    __shared__ float p_lds[64*PP];        // 12544 B: params
    __shared__ float c1_l[64], c2_l[64], u_l[64], zr_l[64];

    const int tid = threadIdx.x;
    const int bid = blockIdx.x;
    const int b  = bid >> 4;              // batch (16 blocks per batch)
    const int j0 = (bid & 15) << 6;       // first site of block
    float* zb = z + b*L_DIM;

    // -------- Phase 0: stencil / context --------
    if (tid < 64){
        int idx = 3*(j0 + tid) + off;
        int im2 = idx-2; if (im2 < 0) im2 += L_DIM;
        int im1 = idx-1; if (im1 < 0) im1 += L_DIM;
        int ip1 = idx+1; if (ip1 >= L_DIM) ip1 -= L_DIM;
        int ip2 = idx+2; if (ip2 >= L_DIM) ip2 -= L_DIM;
        float zi  = zb[idx];
        float zm1 = zb[im1];
        float zm2 = zb[im2];
        float zp1 = zb[ip1];
        float zp2 = zb[ip2];
        c1_l[tid] = mod2pi(zm1 - zm2);    // V[idx-1]
        c2_l[tid] = mod2pi(zp2 - zp1);    // V[idx+2]
        float V   = mod2pi(zi - zm1);     // V[idx]
        float u = V * (1.0f/TWO_PI_F);
        u_l[tid] = fminf(fmaxf(u, EPS_F), 1.0f-EPS_F);
        zr_l[tid] = zm1;
    }
    __syncthreads();

    // -------- Phase 1: h1[m][k] = tanh(c1*W1[0,k] + c2*W1[1,k] + b1[k]), k = tid --------
    {
        float w0 = W1[tid];
        float w1 = W1[H_DIM + tid];
        float bb = b1[tid];
        #pragma unroll 8
        for (int m=0; m<64; m++){
            float pre = fmaf(c1_l[m], w0, fmaf(c2_l[m], w1, bb));
            h_lds[m*HP2 + tid] = fast_tanh(pre);
        }
    }
    __syncthreads();

    // -------- Phase 2: h1(64x256) @ W2(256x256); wave w owns cols [w*64, w*64+64) --------
    const int wv   = tid >> 6;            // wave 0..3 -> col slice
    const int lane = tid & 63;
    const int ty = lane >> 4;             // 0..3
    const int tx = lane & 15;             // 0..15
    const int c4 = wv*16 + tx;            // float4 col index within W2 row

    float acc[16][4];
    #pragma unroll
    for (int s=0; s<16; s++){ acc[s][0]=0.f; acc[s][1]=0.f; acc[s][2]=0.f; acc[s][3]=0.f; }

    const float4* __restrict__ W2v = (const float4*)W2;
    for (int k=0; k<H_DIM; k+=4){
        float4 wq0 = W2v[(k+0)*64 + c4];
        float4 wq1 = W2v[(k+1)*64 + c4];
        float4 wq2 = W2v[(k+2)*64 + c4];
        float4 wq3 = W2v[(k+3)*64 + c4];
        #pragma unroll
        for (int half=0; half<2; half++){
            float4 av[8];
            #pragma unroll
            for (int s=0; s<8; s++)
                av[s] = *(const float4*)&h_lds[((half*8+s)*4+ty)*HP2 + k];  // bcast over tx
            #pragma unroll
            for (int s=0; s<8; s++){
                const int ss = half*8 + s;
                acc[ss][0] = fmaf(av[s].x, wq0.x, acc[ss][0]);
                acc[ss][1] = fmaf(av[s].x, wq0.y, acc[ss][1]);
                acc[ss][2] = fmaf(av[s].x, wq0.z, acc[ss][2]);
                acc[ss][3] = fmaf(av[s].x, wq0.w, acc[ss][3]);
                acc[ss][0] = fmaf(av[s].y, wq1.x, acc[ss][0]);
                acc[ss][1] = fmaf(av[s].y, wq1.y, acc[ss][1]);
                acc[ss][2] = fmaf(av[s].y, wq1.z, acc[ss][2]);
                acc[ss][3] = fmaf(av[s].y, wq1.w, acc[ss][3]);
                acc[ss][0] = fmaf(av[s].z, wq2.x, acc[ss][0]);
                acc[ss][1] = fmaf(av[s].z, wq2.y, acc[ss][1]);
                acc[ss][2] = fmaf(av[s].z, wq2.z, acc[ss][2]);
                acc[ss][3] = fmaf(av[s].z, wq2.w, acc[ss][3]);
                acc[ss][0] = fmaf(av[s].w, wq3.x, acc[ss][0]);
                acc[ss][1] = fmaf(av[s].w, wq3.y, acc[ss][1]);
                acc[ss][2] = fmaf(av[s].w, wq3.z, acc[ss][2]);
                acc[ss][3] = fmaf(av[s].w, wq3.w, acc[ss][3]);
            }
        }
    }
    __syncthreads();      // all h1 reads done

    // -------- Phase 3: h2 = tanh(acc + b2) back into LDS (float4 stores) --------
    {
        const int n0 = wv*64 + tx*4;
        float4 bb = *(const float4*)&b2[n0];
        #pragma unroll
        for (int s=0; s<16; s++){
            int m = s*4 + ty;
            float4 o;
            o.x = fast_tanh(acc[s][0] + bb.x);
            o.y = fast_tanh(acc[s][1] + bb.y);
            o.z = fast_tanh(acc[s][2] + bb.z);
            o.w = fast_tanh(acc[s][3] + bb.w);
            *(float4*)&h_lds[m*HP2 + n0] = o;
        }
    }
    __syncthreads();

    // -------- Phase 4: params(64x48) = h2 @ W3 + b3 --------
    // site = tid&63 (per-lane), output-block = wave index (uniform) -> W3/b3 loads are
    // wave-uniform scalar (s_load) broadcasts: no redundant vector-memory traffic.
    {
        const int m4 = tid & 63;
        const int ol = __builtin_amdgcn_readfirstlane(tid >> 6);   // 0..3, 12 params each
        float acc3[12];
        #pragma unroll
        for (int r=0; r<12; r++) acc3[r] = 0.f;
        const float4* __restrict__ W3v = (const float4*)W3;        // [k][12 float4]
        for (int k=0; k<H_DIM; k+=4){
            float4 hv = *(const float4*)&h_lds[m4*HP2 + k];
            float hw[4] = {hv.x, hv.y, hv.z, hv.w};
            #pragma unroll
            for (int j=0; j<4; j++){
                float h = hw[j];
                float4 q0 = W3v[(k+j)*12 + ol*3 + 0];
                float4 q1 = W3v[(k+j)*12 + ol*3 + 1];
                float4 q2 = W3v[(k+j)*12 + ol*3 + 2];
                acc3[0] = fmaf(h, q0.x, acc3[0]);  acc3[1] = fmaf(h, q0.y, acc3[1]);
                acc3[2] = fmaf(h, q0.z, acc3[2]);  acc3[3] = fmaf(h, q0.w, acc3[3]);
                acc3[4] = fmaf(h, q1.x, acc3[4]);  acc3[5] = fmaf(h, q1.y, acc3[5]);
                acc3[6] = fmaf(h, q1.z, acc3[6]);  acc3[7] = fmaf(h, q1.w, acc3[7]);
                acc3[8] = fmaf(h, q2.x, acc3[8]);  acc3[9] = fmaf(h, q2.y, acc3[9]);
                acc3[10]= fmaf(h, q2.z, acc3[10]); acc3[11]= fmaf(h, q2.w, acc3[11]);
            }
        }
        #pragma unroll
        for (int r=0; r<12; r++)
            p_lds[m4*PP + ol*12 + r] = acc3[r] + b3[ol*12 + r];
    }
    __syncthreads();

    // -------- Phase 5: epilogue, one thread per site (wave 0) --------
    float ll = 0.0f;
    if (tid < 64){
        const float* p = p_lds + tid*PP;  // [0..15] log_scale, [16..31] shift, [32..47] wlogit
        float mx = p[32];
        #pragma unroll
        for (int i=1; i<16; i++) mx = fmaxf(mx, p[32+i]);
        float w[16]; float se = 0.0f;
        #pragma unroll
        for (int i=0; i<16; i++){ w[i] = __expf(p[32+i]-mx); se += w[i]; }
        float inv = __fdividef(0.84f, se);   // (1 - K*MIN_W)/sum

        float u = u_l[tid];
        float a  = u*u;
        float om = 1.0f - u;
        float b_ = om*om;
        float apb = a + b_;
        float s = __fdividef(a, apb);
        float ds_du = __fdividef(2.0f*u*om, apb*apb);
        s = fminf(fmaxf(s, EPS_F), 1.0f-EPS_F);
        float logit_s = __logf(s) - log1pf(-s);

        float y = 0.0f, dd = 0.0f;
        #pragma unroll
        for (int i=0; i<16; i++){
            float alpha = __expf(p[i]);
            float wgt = fmaf(w[i], inv, 0.01f);
            float targ = alpha * (logit_s + p[16+i]);
            float g = __fdividef(1.0f, 1.0f + __expf(-targ));
            y  = fmaf(wgt, g, y);
            dd = fmaf(wgt*alpha, g*(1.0f-g), dd);
        }
        float dy_du = __fdividef(dd, s*(1.0f-s)) * ds_du;
        ll = __logf(dy_du);

        int idx = 3*(j0 + tid) + off;
        zb[idx] = mod2pi(fmaf(TWO_PI_F, y, zr_l[tid]));
    }
    // wave-0 butterfly reduction of ll, one atomic per block
    if (tid < 64){
        #pragma unroll
        for (int o=32; o>0; o>>=1) ll += __shfl_down(ll, o, 64);
        if (tid == 0) atomicAdd(&ldj[b], ll);
    }
}

extern "C" void kernel_launch(void* const* d_in, const int* in_sizes, int n_in,
                              void* d_out, int out_size, void* d_ws, size_t ws_size,
                              hipStream_t stream) {
    const float* z_in = (const float*)d_in[0];
    const float* W1 = (const float*)d_in[1];
    const float* b1 = (const float*)d_in[2];
    const float* W2 = (const float*)d_in[3];
    const float* b2 = (const float*)d_in[4];
    const float* W3 = (const float*)d_in[5];
    const float* b3 = (const float*)d_in[6];
    float* out = (float*)d_out;
    float* zbuf = out;                    // z worked in-place in d_out
    float* ldj  = out + B_DIM*L_DIM;

    init_kernel<<<(B_DIM*L_DIM + 255)/256, 256, 0, stream>>>(z_in, out);

    for (int t=0; t<12; t++){
        int r = t % 3;
        int off = (r==0) ? 0 : ((r==1) ? 2 : 1);
        round_kernel<<<1024, 256, 0, stream>>>(
            zbuf, ldj,
            W1 + t*2*H_DIM, b1 + t*H_DIM,
            W2 + t*H_DIM*H_DIM, b2 + t*H_DIM,
            W3 + t*H_DIM*48, b3 + t*48,
            off);
    }
}